// Round 1
// baseline (67085.803 us; speedup 1.0000x reference)
//
#include <hip/hip_runtime.h>

#define HH    100
#define G4    400      // 4*H
#define LSEQ  168
#define STEPS 48
#define NTICK 8066     // ticks 0..8065 (L0 at tick t, L1 at tick t-1)
#define NPOOL 176      // row-units streamed from L2 instead of registers
#define KPAD  112      // padded K so every pool quarter is 28 wide

__device__ __forceinline__ float sigmoidf_(float x) {
    return 1.0f / (1.0f + __expf(-x));
}
__device__ __forceinline__ float tanhf_(float x) {
    return 1.0f - 2.0f / (__expf(2.0f * x) + 1.0f);
}

// Pool weights, transposed: wsT[k*NPOOL + u], k in [0,112) (k>=100 zero-padded).
// u <  16 : W_hh0 row 384+u   -> gate0 row 384+u      (input h0)
// u < 32  : W_ih1 row 368+u   -> gate1 row 368+u (A)  (input h0)
// u < 176 : W_hh1 row 224+u   -> gate1 row 224+u (B)  (input h1)
__global__ void prep_kernel(const float* __restrict__ Whh0,
                            const float* __restrict__ Wih1,
                            const float* __restrict__ Whh1,
                            float* __restrict__ wsT) {
    int i = blockIdx.x * 256 + threadIdx.x;
    if (i >= KPAD * NPOOL) return;
    int k = i / NPOOL, u = i % NPOOL;
    float v = 0.0f;
    if (k < HH) {
        if (u < 16)       v = Whh0[(384 + u) * HH + k];
        else if (u < 32)  v = Wih1[(368 + u) * HH + k];
        else              v = Whh1[(224 + u) * HH + k];
    }
    wsT[i] = v;
}

__global__ __launch_bounds__(512, 2)
void lstm_kernel(const float* __restrict__ X,     // (512,168)
                 const float* __restrict__ Wih0,  // (400,1)
                 const float* __restrict__ Whh0,  // (400,100)
                 const float* __restrict__ bih0,
                 const float* __restrict__ bhh0,
                 const float* __restrict__ Wih1,  // (400,100)
                 const float* __restrict__ Whh1,  // (400,100)
                 const float* __restrict__ bih1,
                 const float* __restrict__ bhh1,
                 const float* __restrict__ fcw,   // (100)
                 const float* __restrict__ fcb,   // (1)
                 const float* __restrict__ wsT,   // (112,176)
                 float* __restrict__ out)         // (512,48)
{
    __shared__ __align__(16) float sh0[2][KPAD];   // h of layer0, per batch
    __shared__ __align__(16) float sh1[2][KPAD];   // h of layer1
    __shared__ float g0s[2][G4];                   // W_hh0 . h0 partials (rows 0..383)
    __shared__ float g1a[2][G4];                   // W_ih1 . h0 partials (rows 0..383)
    __shared__ float g1b[2][256];                  // W_hh1 . h1 partials (rows 0..255)
    __shared__ __align__(16) float pp[2][NPOOL][4];// pool quarter partials
    __shared__ float sbias0[G4], sbias1[G4], swih0[G4], sfcw[HH];
    __shared__ float yacc[2], ybuf[2];

    const int t  = threadIdx.x;
    const int wg = blockIdx.x;
    const int b0 = wg * 2, b1 = wg * 2 + 1;

    // ---- one-time init ----
    for (int i = t; i < 2 * KPAD; i += 512) {
        ((float*)sh0)[i] = 0.0f;
        ((float*)sh1)[i] = 0.0f;
    }
    if (t < G4) {
        sbias0[t] = bih0[t] + bhh0[t];
        sbias1[t] = bih1[t] + bhh1[t];
        swih0[t]  = Wih0[t];
    }
    if (t < HH) sfcw[t] = fcw[t];
    if (t == 0) { yacc[0] = yacc[1] = 0.0f; ybuf[0] = ybuf[1] = 0.0f; }
    const float fcb0 = fcb[0];

    // register-resident weights: two K=100 row-units per thread
    float w0[HH], w1[HH];
    {
        const float *p0, *p1;
        if (t < 384) { p0 = Whh0 + t * HH;         p1 = Wih1 + t * HH; }
        else         { p0 = Whh1 + (t - 384) * HH; p1 = Whh1 + (t - 256) * HH; }
        #pragma unroll
        for (int k = 0; k < HH; k += 4) {
            float4 a = *(const float4*)(p0 + k);
            w0[k] = a.x; w0[k+1] = a.y; w0[k+2] = a.z; w0[k+3] = a.w;
            float4 b = *(const float4*)(p1 + k);
            w1[k] = b.x; w1[k+1] = b.y; w1[k+2] = b.z; w1[k+3] = b.w;
        }
    }

    // main-FMA input vector (wave-uniform): waves 0..5 read h0, waves 6..7 read h1
    const float* hin = (t < 384) ? &sh0[0][0] : &sh1[0][0];

    // pool task params (quarter 1 = q=t; quarter 2 = q=512+t for t<192)
    const int u1 = t % NPOOL, kq1 = t / NPOOL;
    const int u2 = (160 + t) % NPOOL, kq2 = (512 + t) / NPOOL;
    const bool has2 = (t < 192);
    const float* hq1 = (u1 < 32) ? &sh0[0][0] : &sh1[0][0];
    const float* hq2 = (u2 < 32) ? &sh0[0][0] : &sh1[0][0];
    const float* wp1 = wsT + kq1 * 28 * NPOOL + u1;
    const float* wp2 = wsT + kq2 * 28 * NPOOL + u2;
    const int k01 = kq1 * 28, k02 = kq2 * 28;

    // cell-update params
    float c0 = 0.0f, c1 = 0.0f;
    const int ub = (t < 200) ? (t / 100) : ((t - 200) / 100);
    const int uj = (t < 200) ? (t % 100) : ((t - 200) % 100);
    const float* xrow = X + ((ub == 0) ? b0 : b1) * LSEQ;

    __syncthreads();

    #pragma unroll 1
    for (int tick = 0; tick < NTICK; ++tick) {
        const bool ydtick = (tick >= 2) && ((tick - 2) % LSEQ == LSEQ - 1);

        // ================= Phase A: all FMA work =================
        {
            float a00 = 0.f, a01 = 0.f, a10 = 0.f, a11 = 0.f;
            #pragma unroll
            for (int kc = 0; kc < 25; ++kc) {
                const float4 ha = *(const float4*)(hin + 4 * kc);
                const float4 hb = *(const float4*)(hin + KPAD + 4 * kc);
                const float w00 = w0[4*kc], w01 = w0[4*kc+1], w02 = w0[4*kc+2], w03 = w0[4*kc+3];
                const float w10 = w1[4*kc], w11 = w1[4*kc+1], w12 = w1[4*kc+2], w13 = w1[4*kc+3];
                a00 += w00*ha.x; a01 += w00*hb.x; a10 += w10*ha.x; a11 += w10*hb.x;
                a00 += w01*ha.y; a01 += w01*hb.y; a10 += w11*ha.y; a11 += w11*hb.y;
                a00 += w02*ha.z; a01 += w02*hb.z; a10 += w12*ha.z; a11 += w12*hb.z;
                a00 += w03*ha.w; a01 += w03*hb.w; a10 += w13*ha.w; a11 += w13*hb.w;
            }
            if (t < 384) {
                g0s[0][t] = a00; g0s[1][t] = a01;
                g1a[0][t] = a10; g1a[1][t] = a11;
            } else {
                const int r1 = t - 384, r2 = t - 256;
                g1b[0][r1] = a00; g1b[1][r1] = a01;
                g1b[0][r2] = a10; g1b[1][r2] = a11;
            }
        }
        // pool quarters (weights stream from L2)
        {
            float pa = 0.f, pb = 0.f;
            #pragma unroll
            for (int i = 0; i < 28; i += 4) {
                const float4 hA = *(const float4*)(hq1 + k01 + i);
                const float4 hB = *(const float4*)(hq1 + KPAD + k01 + i);
                const float wa = wp1[(i+0)*NPOOL], wb = wp1[(i+1)*NPOOL];
                const float wc = wp1[(i+2)*NPOOL], wd = wp1[(i+3)*NPOOL];
                pa += wa*hA.x + wb*hA.y + wc*hA.z + wd*hA.w;
                pb += wa*hB.x + wb*hB.y + wc*hB.z + wd*hB.w;
            }
            pp[0][u1][kq1] = pa; pp[1][u1][kq1] = pb;
            if (has2) {
                float qa = 0.f, qb = 0.f;
                #pragma unroll
                for (int i = 0; i < 28; i += 4) {
                    const float4 hA = *(const float4*)(hq2 + k02 + i);
                    const float4 hB = *(const float4*)(hq2 + KPAD + k02 + i);
                    const float wa = wp2[(i+0)*NPOOL], wb = wp2[(i+1)*NPOOL];
                    const float wc = wp2[(i+2)*NPOOL], wd = wp2[(i+3)*NPOOL];
                    qa += wa*hA.x + wb*hA.y + wc*hA.z + wd*hA.w;
                    qb += wa*hB.x + wb*hB.y + wc*hB.z + wd*hB.w;
                }
                pp[0][u2][kq2] = qa; pp[1][u2][kq2] = qb;
            }
        }
        // fc dot (rare: once per 168 ticks), reads stable h1
        if (ydtick && t < 200) {
            atomicAdd(&yacc[ub], sfcw[uj] * sh1[ub][uj]);
        }
        __syncthreads();

        // ================= Phase B: cell updates =================
        if (t < 200) {
            if (tick < 8064) {           // L0 processes global step g0 = tick
                const int s = tick / LSEQ, p = tick % LSEQ;
                float x;
                if (s == 0)            x = xrow[p];
                else if (p < LSEQ - 1) x = xrow[p + 1];
                else                   x = ybuf[ub];
                const int j = uj, b = ub;
                const int ro = 300 + j;
                float Gi = sbias0[j]       + swih0[j]       * x + g0s[b][j];
                float Gf = sbias0[100 + j] + swih0[100 + j] * x + g0s[b][100 + j];
                float Gg = sbias0[200 + j] + swih0[200 + j] * x + g0s[b][200 + j];
                float po = (ro < 384) ? g0s[b][ro]
                                      : (pp[b][ro-384][0] + pp[b][ro-384][1] +
                                         pp[b][ro-384][2] + pp[b][ro-384][3]);
                float Go = sbias0[ro] + swih0[ro] * x + po;
                c0 = sigmoidf_(Gf) * c0 + sigmoidf_(Gi) * tanhf_(Gg);
                sh0[b][j] = sigmoidf_(Go) * tanhf_(c0);
            }
        } else if (t < 400) {
            if (tick >= 1 && tick <= 8064) {   // L1 processes g1 = tick-1
                const int j = uj, b = ub;
                const int rg = 200 + j, ro = 300 + j;
                float Gi = sbias1[j]       + g1a[b][j]       + g1b[b][j];
                float Gf = sbias1[100 + j] + g1a[b][100 + j] + g1b[b][100 + j];
                float Bg = (rg < 256) ? g1b[b][rg]
                                      : (pp[b][rg-224][0] + pp[b][rg-224][1] +
                                         pp[b][rg-224][2] + pp[b][rg-224][3]);
                float Gg = sbias1[rg] + g1a[b][rg] + Bg;
                float Ao = (ro < 384) ? g1a[b][ro]
                                      : (pp[b][ro-368][0] + pp[b][ro-368][1] +
                                         pp[b][ro-368][2] + pp[b][ro-368][3]);
                float Bo = pp[b][ro-224][0] + pp[b][ro-224][1] +
                           pp[b][ro-224][2] + pp[b][ro-224][3];
                float Go = sbias1[ro] + Ao + Bo;
                c1 = sigmoidf_(Gf) * c1 + sigmoidf_(Gi) * tanhf_(Gg);
                sh1[b][j] = sigmoidf_(Go) * tanhf_(c1);
            }
        } else if (t == 400) {
            if (ydtick) {                 // finalize y for chunk s
                const int s = (tick - 2) / LSEQ;
                float y0 = yacc[0] + fcb0;
                float y1 = yacc[1] + fcb0;
                ybuf[0] = y0; ybuf[1] = y1;
                out[b0 * STEPS + s] = y0;
                out[b1 * STEPS + s] = y1;
                yacc[0] = 0.0f; yacc[1] = 0.0f;
            }
        }
        __syncthreads();
    }
}

extern "C" void kernel_launch(void* const* d_in, const int* in_sizes, int n_in,
                              void* d_out, int out_size, void* d_ws, size_t ws_size,
                              hipStream_t stream) {
    const float* X    = (const float*)d_in[0];
    const float* Wih0 = (const float*)d_in[1];
    const float* Whh0 = (const float*)d_in[2];
    const float* bih0 = (const float*)d_in[3];
    const float* bhh0 = (const float*)d_in[4];
    const float* Wih1 = (const float*)d_in[5];
    const float* Whh1 = (const float*)d_in[6];
    const float* bih1 = (const float*)d_in[7];
    const float* bhh1 = (const float*)d_in[8];
    const float* fcw  = (const float*)d_in[9];
    const float* fcb  = (const float*)d_in[10];
    float* out = (float*)d_out;
    float* wsT = (float*)d_ws;   // 112*176 floats = 78,848 B of scratch

    hipLaunchKernelGGL(prep_kernel, dim3((KPAD * NPOOL) / 256), dim3(256), 0, stream,
                       Whh0, Wih1, Whh1, wsT);
    hipLaunchKernelGGL(lstm_kernel, dim3(256), dim3(512), 0, stream,
                       X, Wih0, Whh0, bih0, bhh0, Wih1, Whh1, bih1, bhh1,
                       fcw, fcb, wsT, out);
}